// Round 25
// baseline (831.220 us; speedup 1.0000x reference)
//
#include <hip/hip_runtime.h>

#define S_LEN 2048
#define QKV_N 4096
// SCALE_Q * log2(e): logits land in log2 domain, softmax uses v_exp_f32 (exp2)
#define SCALE_Q_LOG2E 0.12751744461f

typedef __attribute__((ext_vector_type(8))) short short8;
typedef __attribute__((ext_vector_type(4))) float f32x4;
typedef __attribute__((ext_vector_type(16))) float f32x16;
typedef __attribute__((ext_vector_type(4))) float floatv4;
typedef __attribute__((ext_vector_type(4))) unsigned short ushortv4;
typedef __attribute__((ext_vector_type(2))) unsigned int uint2v;

__device__ __forceinline__ float bf2f(unsigned short u) {
  union { unsigned u; float f; } x; x.u = ((unsigned)u) << 16; return x.f;
}
__device__ __forceinline__ unsigned short f2bf(float f) {
  union { float f; unsigned u; } x; x.f = f;
  unsigned r = x.u + 0x7fffu + ((x.u >> 16) & 1u);
  return (unsigned short)(r >> 16);
}

typedef const unsigned int __attribute__((address_space(1)))* gas1_t;
typedef unsigned int __attribute__((address_space(3)))* las3_t;
#define GLL16(g, l) __builtin_amdgcn_global_load_lds((gas1_t)(const void*)(g), (las3_t)(void*)(l), 16, 0, 0)

// fast exp2: raw v_exp_f32, no libm fixup path
#define EXP2F(x) __builtin_amdgcn_exp2f(x)

// ---------------- fused prep: cvt (hidden f32->bf16) + 2 transposes ----------------
__global__ __launch_bounds__(256) void k_prep(const float* __restrict__ hidden,
                                              unsigned short* __restrict__ hA,
                                              const float* __restrict__ w_qkv,
                                              unsigned short* __restrict__ wqkvT,
                                              const float* __restrict__ w_o,
                                              unsigned short* __restrict__ woT) {
  __shared__ float t[64][65];
  const int blk = blockIdx.x;
  if (blk < 16384) {
    int i = blk * 256 + threadIdx.x;
    floatv4 v = ((const floatv4*)hidden)[i];
    ushortv4 o;
    o[0] = f2bf(v[0]); o[1] = f2bf(v[1]); o[2] = f2bf(v[2]); o[3] = f2bf(v[3]);
    ((ushortv4*)hA)[i] = o;
    return;
  }
  const float* in;
  unsigned short* out;
  int bx, by, R, C;
  if (blk < 18432) {
    in = w_qkv; out = wqkvT; R = 2048; C = 4096;
    int bi = blk - 16384; bx = bi & 63; by = bi >> 6;
  } else {
    in = w_o; out = woT; R = 2048; C = 2048;
    int bi = blk - 18432; bx = bi & 31; by = bi >> 5;
  }
#pragma unroll
  for (int i = 0; i < 16; ++i) {
    int idx = threadIdx.x + i * 256;
    int r = idx >> 6, c = idx & 63;
    t[r][c] = in[(size_t)(by * 64 + r) * C + bx * 64 + c];
  }
  __syncthreads();
#pragma unroll
  for (int i = 0; i < 16; ++i) {
    int idx = threadIdx.x + i * 256;
    int r = idx >> 6, c = idx & 63;
    out[(size_t)(bx * 64 + r) * R + by * 64 + c] = f2bf(t[c][r]);
  }
}

// ---------------- 256x256x(BK=64) bf16 GEMM, 8 waves, 4-phase pipelined ----------------
// R19/R21-exact (measured best): 4M x 2N waves (wave = one head in MODE 1),
// fused norm+rope epilogue, setprio ON (R18 A/B: +5us/GEMM here), vmcnt(0)
// drain at p==3 (structurally required -- R20 post-mortem).
template <int MODE>
__global__ __launch_bounds__(512, 2) void k_gemm256(const unsigned short* __restrict__ A,
                                                    const unsigned short* __restrict__ BT,
                                                    void* __restrict__ Cout,
                                                    int M, int N, int K,
                                                    const int* __restrict__ pos,
                                                    const float* __restrict__ qw,
                                                    const float* __restrict__ kw) {
  const int tid = threadIdx.x;
  const int lane = tid & 63;
  const int wid = tid >> 6;
  const int wr = wid >> 1;          // 0..3 over M (64 rows each)
  const int wc = wid & 1;           // 0..1 over N (128 cols each)
  const int lr = lane & 15, lg = lane >> 4;

  // T1: bijective XCD-aware block swizzle (nwg % 8 == 0)
  const int gx = gridDim.x;
  const int nwg = gx * gridDim.y;
  const int lid = blockIdx.y * gx + blockIdx.x;
  const int qc = nwg >> 3;
  const int swz = (lid & 7) * qc + (lid >> 3);
  const int row0 = (swz / gx) * 256, col0 = (swz % gx) * 256;

  __shared__ __align__(16) unsigned short As[2][256 * 64];
  __shared__ __align__(16) unsigned short Bs[2][256 * 64];

  f32x4 acc[4][8];
#pragma unroll
  for (int m = 0; m < 4; ++m)
#pragma unroll
    for (int n = 0; n < 8; ++n) acc[m][n] = (f32x4){0.f, 0.f, 0.f, 0.f};

  const int r1 = tid >> 3, c1 = tid & 7;
  const int r2 = (tid + 512) >> 3, c2 = (tid + 512) & 7;
  const size_t so1 = (size_t)r1 * K + (size_t)((c1 ^ (r1 & 7)) * 8);
  const size_t so2 = (size_t)r2 * K + (size_t)((c2 ^ (r2 & 7)) * 8);
  const unsigned ld1 = (unsigned)tid * 16, ld2 = (unsigned)(tid + 512) * 16;

  const unsigned short* Abase = A + (size_t)row0 * K;
  const unsigned short* Bbase = BT + (size_t)col0 * K;

  auto stage = [&](int ph, int kt, int buf) {
    const size_t hb = (size_t)(ph >> 1) * 128 * K + (size_t)kt * 64;
    const unsigned short* src;
    unsigned short* dst;
    if (ph & 1) { src = Bbase + hb; dst = &Bs[buf][(ph >> 1) * 128 * 64]; }
    else        { src = Abase + hb; dst = &As[buf][(ph >> 1) * 128 * 64]; }
    GLL16(src + so1, (char*)dst + ld1);
    GLL16(src + so2, (char*)dst + ld2);
  };

#pragma unroll
  for (int ph = 0; ph < 4; ++ph) stage(ph, 0, 0);
  asm volatile("s_waitcnt vmcnt(0)" ::: "memory");
  __builtin_amdgcn_s_barrier();

  const int NT = K >> 6;
  for (int t = 0; t < NT; ++t) {
    const int cur = t & 1;
    const char* Ab = (const char*)&As[cur][0];
    const char* Bb = (const char*)&Bs[cur][0];
    short8 af[4];
#pragma unroll
    for (int p = 0; p < 4; ++p) {
      const int ks = p >> 1, half = p & 1;
      short8 bf[4];
      if (half == 0) {
#pragma unroll
        for (int m = 0; m < 4; ++m) {
          int rA = wr * 64 + m * 16 + lr;
          af[m] = *(const short8*)(Ab +
                  ((rA * 128 + (ks * 4 + lg) * 16) ^ ((rA & 7) << 4)));
        }
      }
#pragma unroll
      for (int n = 0; n < 4; ++n) {
        int rB = wc * 128 + (half * 4 + n) * 16 + lr;
        bf[n] = *(const short8*)(Bb +
                ((rB * 128 + (ks * 4 + lg) * 16) ^ ((rB & 7) << 4)));
      }
      if (t + 1 < NT) stage(p, t + 1, cur ^ 1);
      __builtin_amdgcn_sched_barrier(0);
      __builtin_amdgcn_s_setprio(1);
#pragma unroll
      for (int m = 0; m < 4; ++m)
#pragma unroll
        for (int n = 0; n < 4; ++n)
          acc[m][half * 4 + n] = __builtin_amdgcn_mfma_f32_16x16x32_bf16(
              af[m], bf[n], acc[m][half * 4 + n], 0, 0, 0);
      __builtin_amdgcn_s_setprio(0);
      if (p == 3) asm volatile("s_waitcnt vmcnt(0)" ::: "memory");
      __builtin_amdgcn_s_barrier();
    }
  }

  if constexpr (MODE == 0) {
    float* C = (float*)Cout;
#pragma unroll
    for (int m = 0; m < 4; ++m)
#pragma unroll
      for (int n = 0; n < 8; ++n)
#pragma unroll
        for (int r = 0; r < 4; ++r)
          C[(size_t)(row0 + wr * 64 + m * 16 + 4 * lg + r) * N +
            col0 + wc * 128 + n * 16 + lr] = acc[m][n][r];
  } else {
    // MODE 1: qkv output with fused per-head RMSNorm + RoPE (v: plain).
    unsigned short* C = (unsigned short*)Cout;
    const int hcol0 = col0 + wc * 128;       // head-aligned (128-col) base
    if (col0 >= 3072) {                       // v region: plain bf16
#pragma unroll
      for (int m = 0; m < 4; ++m)
#pragma unroll
        for (int n = 0; n < 8; ++n)
#pragma unroll
          for (int r = 0; r < 4; ++r)
            C[(size_t)(row0 + wr * 64 + m * 16 + 4 * lg + r) * N +
              hcol0 + n * 16 + lr] = f2bf(acc[m][n][r]);
    } else {
      const bool isq = (col0 < 2048);
      const float scq = isq ? SCALE_Q_LOG2E : 1.0f;
      const float* w = isq ? qw : kw;
      float wv[8], fr[4];
#pragma unroll
      for (int n = 0; n < 8; ++n) wv[n] = w[n * 16 + lr];
#pragma unroll
      for (int j = 0; j < 4; ++j)
        fr[j] = exp2f(-(float)(j * 16 + lr) * 0.20762050593045951f);
#pragma unroll
      for (int m = 0; m < 4; ++m)
#pragma unroll
        for (int r = 0; r < 4; ++r) {
          const int row = row0 + wr * 64 + m * 16 + 4 * lg + r;
          // RMS over the head's 128 cols: in-lane n-sum + lr shfl tree
          float ss = 0.f;
#pragma unroll
          for (int n = 0; n < 8; ++n) ss += acc[m][n][r] * acc[m][n][r];
#pragma unroll
          for (int st = 1; st < 16; st <<= 1) ss += __shfl_xor(ss, st, 64);
          float rn = rsqrtf(ss * (1.0f / 128.0f) + 1e-6f);
          float p = (float)pos[row];
          unsigned short* Cr = C + (size_t)row * N + hcol0;
#pragma unroll
          for (int n = 0; n < 4; ++n) {
            float x1 = acc[m][n][r] * rn * wv[n];
            float x2 = acc[m][n + 4][r] * rn * wv[n + 4];
            float ang = p * fr[n];
            float cs = __cosf(ang), sn = __sinf(ang);
            Cr[n * 16 + lr]       = f2bf((x1 * cs - x2 * sn) * scq);
            Cr[(n + 4) * 16 + lr] = f2bf((x2 * cs + x1 * sn) * scq);
          }
        }
    }
  }
}

// ---------------- flash attention, 16-warp swapped-QK^T structure ----------------
// grid (S/512, B*NH); 16 waves x 32 q-rows (QBLK=512). KVBLK=128, 32x32x16.
// R25: wave count 8 -> 16 (1024 threads). LDS still 128KB -> 1 block/CU, but
// waves/SIMD 2 -> 4 (VGPR=128 is exactly the 4-wave boundary, pinned via
// launch_bounds(1024,4)) -> doubled TLP for MFMA/VALU/trans overlap.
// Per-wave inner mechanics byte-identical to R24.
__global__ __launch_bounds__(1024, 4) void k_attn(const unsigned short* __restrict__ qkv,
                                                  unsigned short* __restrict__ ctx) {
  const int tid = threadIdx.x;
  const int lane = tid & 63;
  const int wid = tid >> 6;           // 0..15
  const int hi = lane >> 5;
  const int l15 = lane & 15;
  const int q31 = lane & 31;
  // XCD remap (bijective over 256 blocks): each XCD gets 8 consecutive bh
  // (= 4 (b,kvh) K/V sets = 2MB, L2-fits), 4 qb each.
  const int lid0 = blockIdx.y * 4 + blockIdx.x;
  const int xcd = lid0 & 7, idx = lid0 >> 3;
  const int bh = xcd * 8 + (idx & 7);
  const int qb = idx >> 3;            // 0..3
  const int b = bh >> 4, h = bh & 15, kvh = h >> 1;

  __shared__ __align__(16) unsigned short Ks[2][128 * 128];
  __shared__ __align__(16) unsigned short Vs[2][128 * 128];

  const size_t baseRow = (size_t)b * S_LEN;
  const int qrow = qb * 512 + wid * 32 + q31;

  const unsigned short* Qg = qkv + (baseRow + qrow) * QKV_N + h * 128;
  short8 qf[8];
#pragma unroll
  for (int c = 0; c < 8; ++c)
    qf[c] = *(const short8*)(Qg + c * 16 + hi * 8);

  const unsigned short* Kg = qkv + baseRow * QKV_N + 2048 + kvh * 128;
  const unsigned short* Vg = Kg + 1024;

  size_t ksrc[2], vsrc[2];
  unsigned sdst[2];
#pragma unroll
  for (int i = 0; i < 2; ++i) {
    int s = tid + i * 1024;             // 0..2047: 2048 16B chunks per 32KB tile
    int krow = s >> 4, kc = s & 15;     // 128 rows x 16 chunks
    ksrc[i] = (size_t)krow * QKV_N + (size_t)((kc ^ (krow & 7)) * 8);
    int st = s >> 3, in8 = s & 7;       // 256 subtiles x 8 chunks
    int vkey = (st >> 3) * 4 + (in8 >> 1);   // 0..127
    int vj = ((st & 7) << 1) | (in8 & 1);    // 0..15
    vsrc[i] = (size_t)vkey * QKV_N + (size_t)(vj * 8);
    sdst[i] = (unsigned)s * 16;
  }

#define STAGE(T, BUF)                                                    \
  {                                                                      \
    size_t toff = (size_t)(T) * 128 * QKV_N;                             \
    GLL16(Kg + toff + ksrc[0], (char*)Ks[BUF] + sdst[0]);                \
    GLL16(Kg + toff + ksrc[1], (char*)Ks[BUF] + sdst[1]);                \
    GLL16(Vg + toff + vsrc[0], (char*)Vs[BUF] + sdst[0]);                \
    GLL16(Vg + toff + vsrc[1], (char*)Vs[BUF] + sdst[1]);                \
  }

  f32x16 acc[4];
#pragma unroll
  for (int d = 0; d < 4; ++d)
#pragma unroll
    for (int r = 0; r < 16; ++r) acc[d][r] = 0.f;
  float m_run = -1e30f, l_run = 0.f;

  const unsigned vbase = (unsigned)(uintptr_t)&Vs[0][0];
  const int sw = (q31 & 7) << 4;

  // issue 8 tr-reads for one ks-group into vr[8]
  auto tr_issue = [&](uint2v* vr, int ksg, unsigned vb) {
#pragma unroll
    for (int db = 0; db < 4; ++db)
#pragma unroll
      for (int rd = 0; rd < 2; ++rd) {
        int st = (ksg * 4 + hi * 2 + rd) * 8 + db * 2 + ((lane >> 4) & 1);
        unsigned a = vb + (unsigned)(st * 128 + l15 * 8);
        asm volatile("ds_read_b64_tr_b16 %0, %1" : "=v"(vr[db * 2 + rd]) : "v"(a));
      }
  };

  STAGE(0, 0);

  for (int t = 0; t < 16; ++t) {
    const int cur = t & 1;
    asm volatile("s_waitcnt vmcnt(0)" ::: "memory");
    __builtin_amdgcn_s_barrier();
    __builtin_amdgcn_sched_barrier(0);
    if (t < 15) STAGE(t + 1, cur ^ 1);

    // ---- QK^T (swapped): p[key][q], lane owns q-row = lane&31 ----
    const char* Kb = (const char*)Ks[cur];
    f32x16 p0, p1, p2, p3;
#pragma unroll
    for (int r = 0; r < 16; ++r) { p0[r] = 0.f; p1[r] = 0.f; p2[r] = 0.f; p3[r] = 0.f; }
#pragma unroll
    for (int c = 0; c < 8; ++c) {
      int cb = c * 32 + hi * 16;
      short8 k0 = *(const short8*)(Kb + (q31      ) * 256 + (cb ^ sw));
      short8 k1 = *(const short8*)(Kb + (q31 + 32 ) * 256 + (cb ^ sw));
      short8 k2 = *(const short8*)(Kb + (q31 + 64 ) * 256 + (cb ^ sw));
      short8 k3 = *(const short8*)(Kb + (q31 + 96 ) * 256 + (cb ^ sw));
      p0 = __builtin_amdgcn_mfma_f32_32x32x16_bf16(k0, qf[c], p0, 0, 0, 0);
      p1 = __builtin_amdgcn_mfma_f32_32x32x16_bf16(k1, qf[c], p1, 0, 0, 0);
      p2 = __builtin_amdgcn_mfma_f32_32x32x16_bf16(k2, qf[c], p2, 0, 0, 0);
      p3 = __builtin_amdgcn_mfma_f32_32x32x16_bf16(k3, qf[c], p3, 0, 0, 0);
    }

    // ---- online softmax (log2 domain, raw v_exp_f32), in-lane ----
    float mt = p0[0];
#pragma unroll
    for (int r = 1; r < 16; ++r) mt = fmaxf(mt, p0[r]);
#pragma unroll
    for (int r = 0; r < 16; ++r) mt = fmaxf(mt, p1[r]);
#pragma unroll
    for (int r = 0; r < 16; ++r) mt = fmaxf(mt, p2[r]);
#pragma unroll
    for (int r = 0; r < 16; ++r) mt = fmaxf(mt, p3[r]);
    mt = fmaxf(mt, __shfl_xor(mt, 32, 64));
    if (!__all(mt - m_run <= 8.0f)) {     // defer-max: P bounded by 2^8
      float mnew = fmaxf(m_run, mt);
      float corr = EXP2F(m_run - mnew);
      l_run *= corr;
#pragma unroll
      for (int d = 0; d < 4; ++d)
#pragma unroll
        for (int r = 0; r < 16; ++r) acc[d][r] *= corr;
      m_run = mnew;
    }
    float s_loc = 0.f;
#pragma unroll
    for (int r = 0; r < 16; ++r) { p0[r] = EXP2F(p0[r] - m_run); s_loc += p0[r]; }
#pragma unroll
    for (int r = 0; r < 16; ++r) { p1[r] = EXP2F(p1[r] - m_run); s_loc += p1[r]; }
#pragma unroll
    for (int r = 0; r < 16; ++r) { p2[r] = EXP2F(p2[r] - m_run); s_loc += p2[r]; }
#pragma unroll
    for (int r = 0; r < 16; ++r) { p3[r] = EXP2F(p3[r] - m_run); s_loc += p3[r]; }
    l_run += s_loc + __shfl_xor(s_loc, 32, 64);

    // ---- PV (swapped): acc[d][q] += V^T x P; tr-reads pipelined 1 group ahead ----
    const unsigned vb = vbase + (unsigned)cur * 32768u;
    const float* pp0 = (const float*)&p0;
    const float* pp1 = (const float*)&p1;
    const float* pp2 = (const float*)&p2;
    const float* pp3 = (const float*)&p3;
    uint2v vrA[8], vrB[8];
    tr_issue(vrA, 0, vb);
#pragma unroll
    for (int ks = 0; ks < 8; ++ks) {
      const int pv = ks >> 1;
      const float* pb = (pv == 0) ? pp0 : (pv == 1) ? pp1 : (pv == 2) ? pp2 : pp3;
      const float* pr = pb + (ks & 1) * 8;
      unsigned t0, t1, u0, u1;
      asm("v_cvt_pk_bf16_f32 %0, %1, %2" : "=v"(t0) : "v"(pr[0]), "v"(pr[1]));
      asm("v_cvt_pk_bf16_f32 %0, %1, %2" : "=v"(t1) : "v"(pr[2]), "v"(pr[3]));
      asm("v_cvt_pk_bf16_f32 %0, %1, %2" : "=v"(u0) : "v"(pr[4]), "v"(pr[5]));
      asm("v_cvt_pk_bf16_f32 %0, %1, %2" : "=v"(u1) : "v"(pr[6]), "v"(pr[7]));
      // cross-half repack in VALU (R3/R4/R9-validated): distinct source values,
      // no CSE-aliasing hazard (t0!=u0, t1!=u1 by construction)
      asm("v_permlane32_swap_b32 %0, %1" : "+v"(t0), "+v"(u0));
      asm("v_permlane32_swap_b32 %0, %1" : "+v"(t1), "+v"(u1));
      union { unsigned u[4]; short8 s; } pa;
      pa.u[0] = t0; pa.u[1] = t1; pa.u[2] = u0; pa.u[3] = u1;

      if (ks + 1 < 8) tr_issue((ks & 1) ? vrA : vrB, ks + 1, vb);

      if (ks < 7) asm volatile("s_waitcnt lgkmcnt(8)" ::: "memory");
      else        asm volatile("s_waitcnt lgkmcnt(0)" ::: "memory");
      __builtin_amdgcn_sched_barrier(0);
#pragma unroll
      for (int db = 0; db < 4; ++db) {
        union { uint2v v[2]; short8 s; } vf;
        if (ks & 1) { vf.v[0] = vrB[db * 2]; vf.v[1] = vrB[db * 2 + 1]; }
        else        { vf.v[0] = vrA[db * 2]; vf.v[1] = vrA[db * 2 + 1]; }
        acc[db] = __builtin_amdgcn_mfma_f32_32x32x16_bf16(vf.s, pa.s, acc[db], 0, 0, 0);
      }
    }
  }

  // ---- epilogue: O^T accum -> ctx[q][d], lane writes its own q-row ----
  float inv = 1.0f / l_run;
  unsigned short* Co = ctx + (baseRow + qrow) * 2048 + h * 128;
#pragma unroll
  for (int db = 0; db < 4; ++db)
#pragma unroll
    for (int g = 0; g < 4; ++g) {
      ushortv4 v;
#pragma unroll
      for (int j = 0; j < 4; ++j) v[j] = f2bf(acc[db][4 * g + j] * inv);
      *(ushortv4*)(Co + db * 32 + g * 8 + hi * 4) = v;
    }
#undef STAGE
}

extern "C" void kernel_launch(void* const* d_in, const int* in_sizes, int n_in,
                              void* d_out, int out_size, void* d_ws, size_t ws_size,
                              hipStream_t stream) {
  const int* positions = (const int*)d_in[0];
  const float* hidden = (const float*)d_in[1];
  const float* w_qkv = (const float*)d_in[2];
  const float* q_norm_w = (const float*)d_in[3];
  const float* k_norm_w = (const float*)d_in[4];
  const float* w_o = (const float*)d_in[5];
  float* out = (float*)d_out;

  char* ws = (char*)d_ws;
  unsigned short* hA    = (unsigned short*)(ws);              // 8192x2048 bf16, reused as ctx
  unsigned short* wqkvT = (unsigned short*)(ws + 33554432);   // 4096x2048 bf16
  unsigned short* woT   = (unsigned short*)(ws + 50331648);   // 2048x2048 bf16
  unsigned short* qkv   = (unsigned short*)(ws + 58720256);   // 8192x4096 bf16
  unsigned short* ctx   = hA;

  // fused prep: cvt + both weight transposes in one launch
  k_prep<<<19456, 256, 0, stream>>>(hidden, hA, w_qkv, wqkvT, w_o, woT);
  // qkv = hidden @ w_qkv with fused RMSNorm+RoPE epilogue (M=8192,N=4096,K=2048)
  k_gemm256<1><<<dim3(16, 32), 512, 0, stream>>>(hA, wqkvT, qkv, 8192, 4096, 2048,
                                                 positions, q_norm_w, k_norm_w);
  k_attn<<<dim3(4, 64), 1024, 0, stream>>>(qkv, ctx);
  // out = ctx @ w_o : M=8192, N=2048, K=2048, f32 out
  k_gemm256<0><<<dim3(8, 32), 512, 0, stream>>>(ctx, woT, out, 8192, 2048, 2048,
                                                nullptr, nullptr, nullptr);
}

// Round 26
// 370.330 us; speedup vs baseline: 2.2445x; 2.2445x over previous
//
#include <hip/hip_runtime.h>

#define S_LEN 2048
#define QKV_N 4096
// SCALE_Q * log2(e): logits land in log2 domain, softmax uses v_exp_f32 (exp2)
#define SCALE_Q_LOG2E 0.12751744461f

typedef __attribute__((ext_vector_type(8))) short short8;
typedef __attribute__((ext_vector_type(4))) float f32x4;
typedef __attribute__((ext_vector_type(16))) float f32x16;
typedef __attribute__((ext_vector_type(4))) float floatv4;
typedef __attribute__((ext_vector_type(4))) unsigned short ushortv4;
typedef __attribute__((ext_vector_type(2))) unsigned int uint2v;

__device__ __forceinline__ float bf2f(unsigned short u) {
  union { unsigned u; float f; } x; x.u = ((unsigned)u) << 16; return x.f;
}
__device__ __forceinline__ unsigned short f2bf(float f) {
  union { float f; unsigned u; } x; x.f = f;
  unsigned r = x.u + 0x7fffu + ((x.u >> 16) & 1u);
  return (unsigned short)(r >> 16);
}

typedef const unsigned int __attribute__((address_space(1)))* gas1_t;
typedef unsigned int __attribute__((address_space(3)))* las3_t;
#define GLL16(g, l) __builtin_amdgcn_global_load_lds((gas1_t)(const void*)(g), (las3_t)(void*)(l), 16, 0, 0)

// fast exp2: raw v_exp_f32, no libm fixup path
#define EXP2F(x) __builtin_amdgcn_exp2f(x)

// ---------------- fused prep: cvt (hidden f32->bf16) + 2 transposes ----------------
__global__ __launch_bounds__(256) void k_prep(const float* __restrict__ hidden,
                                              unsigned short* __restrict__ hA,
                                              const float* __restrict__ w_qkv,
                                              unsigned short* __restrict__ wqkvT,
                                              const float* __restrict__ w_o,
                                              unsigned short* __restrict__ woT) {
  __shared__ float t[64][65];
  const int blk = blockIdx.x;
  if (blk < 16384) {
    int i = blk * 256 + threadIdx.x;
    floatv4 v = ((const floatv4*)hidden)[i];
    ushortv4 o;
    o[0] = f2bf(v[0]); o[1] = f2bf(v[1]); o[2] = f2bf(v[2]); o[3] = f2bf(v[3]);
    ((ushortv4*)hA)[i] = o;
    return;
  }
  const float* in;
  unsigned short* out;
  int bx, by, R, C;
  if (blk < 18432) {
    in = w_qkv; out = wqkvT; R = 2048; C = 4096;
    int bi = blk - 16384; bx = bi & 63; by = bi >> 6;
  } else {
    in = w_o; out = woT; R = 2048; C = 2048;
    int bi = blk - 18432; bx = bi & 31; by = bi >> 5;
  }
#pragma unroll
  for (int i = 0; i < 16; ++i) {
    int idx = threadIdx.x + i * 256;
    int r = idx >> 6, c = idx & 63;
    t[r][c] = in[(size_t)(by * 64 + r) * C + bx * 64 + c];
  }
  __syncthreads();
#pragma unroll
  for (int i = 0; i < 16; ++i) {
    int idx = threadIdx.x + i * 256;
    int r = idx >> 6, c = idx & 63;
    out[(size_t)(bx * 64 + r) * R + by * 64 + c] = f2bf(t[c][r]);
  }
}

// ---------------- 256x256x(BK=64) bf16 GEMM, 8 waves, 4-phase pipelined ----------------
// R19/R21-exact (measured best): 4M x 2N waves (wave = one head in MODE 1),
// fused norm+rope epilogue, setprio ON (R18 A/B: +5us/GEMM here), vmcnt(0)
// drain at p==3 (structurally required -- R20 post-mortem).
template <int MODE>
__global__ __launch_bounds__(512, 2) void k_gemm256(const unsigned short* __restrict__ A,
                                                    const unsigned short* __restrict__ BT,
                                                    void* __restrict__ Cout,
                                                    int M, int N, int K,
                                                    const int* __restrict__ pos,
                                                    const float* __restrict__ qw,
                                                    const float* __restrict__ kw) {
  const int tid = threadIdx.x;
  const int lane = tid & 63;
  const int wid = tid >> 6;
  const int wr = wid >> 1;          // 0..3 over M (64 rows each)
  const int wc = wid & 1;           // 0..1 over N (128 cols each)
  const int lr = lane & 15, lg = lane >> 4;

  // T1: bijective XCD-aware block swizzle (nwg % 8 == 0)
  const int gx = gridDim.x;
  const int nwg = gx * gridDim.y;
  const int lid = blockIdx.y * gx + blockIdx.x;
  const int qc = nwg >> 3;
  const int swz = (lid & 7) * qc + (lid >> 3);
  const int row0 = (swz / gx) * 256, col0 = (swz % gx) * 256;

  __shared__ __align__(16) unsigned short As[2][256 * 64];
  __shared__ __align__(16) unsigned short Bs[2][256 * 64];

  f32x4 acc[4][8];
#pragma unroll
  for (int m = 0; m < 4; ++m)
#pragma unroll
    for (int n = 0; n < 8; ++n) acc[m][n] = (f32x4){0.f, 0.f, 0.f, 0.f};

  const int r1 = tid >> 3, c1 = tid & 7;
  const int r2 = (tid + 512) >> 3, c2 = (tid + 512) & 7;
  const size_t so1 = (size_t)r1 * K + (size_t)((c1 ^ (r1 & 7)) * 8);
  const size_t so2 = (size_t)r2 * K + (size_t)((c2 ^ (r2 & 7)) * 8);
  const unsigned ld1 = (unsigned)tid * 16, ld2 = (unsigned)(tid + 512) * 16;

  const unsigned short* Abase = A + (size_t)row0 * K;
  const unsigned short* Bbase = BT + (size_t)col0 * K;

  auto stage = [&](int ph, int kt, int buf) {
    const size_t hb = (size_t)(ph >> 1) * 128 * K + (size_t)kt * 64;
    const unsigned short* src;
    unsigned short* dst;
    if (ph & 1) { src = Bbase + hb; dst = &Bs[buf][(ph >> 1) * 128 * 64]; }
    else        { src = Abase + hb; dst = &As[buf][(ph >> 1) * 128 * 64]; }
    GLL16(src + so1, (char*)dst + ld1);
    GLL16(src + so2, (char*)dst + ld2);
  };

#pragma unroll
  for (int ph = 0; ph < 4; ++ph) stage(ph, 0, 0);
  asm volatile("s_waitcnt vmcnt(0)" ::: "memory");
  __builtin_amdgcn_s_barrier();

  const int NT = K >> 6;
  for (int t = 0; t < NT; ++t) {
    const int cur = t & 1;
    const char* Ab = (const char*)&As[cur][0];
    const char* Bb = (const char*)&Bs[cur][0];
    short8 af[4];
#pragma unroll
    for (int p = 0; p < 4; ++p) {
      const int ks = p >> 1, half = p & 1;
      short8 bf[4];
      if (half == 0) {
#pragma unroll
        for (int m = 0; m < 4; ++m) {
          int rA = wr * 64 + m * 16 + lr;
          af[m] = *(const short8*)(Ab +
                  ((rA * 128 + (ks * 4 + lg) * 16) ^ ((rA & 7) << 4)));
        }
      }
#pragma unroll
      for (int n = 0; n < 4; ++n) {
        int rB = wc * 128 + (half * 4 + n) * 16 + lr;
        bf[n] = *(const short8*)(Bb +
                ((rB * 128 + (ks * 4 + lg) * 16) ^ ((rB & 7) << 4)));
      }
      if (t + 1 < NT) stage(p, t + 1, cur ^ 1);
      __builtin_amdgcn_sched_barrier(0);
      __builtin_amdgcn_s_setprio(1);
#pragma unroll
      for (int m = 0; m < 4; ++m)
#pragma unroll
        for (int n = 0; n < 4; ++n)
          acc[m][half * 4 + n] = __builtin_amdgcn_mfma_f32_16x16x32_bf16(
              af[m], bf[n], acc[m][half * 4 + n], 0, 0, 0);
      __builtin_amdgcn_s_setprio(0);
      if (p == 3) asm volatile("s_waitcnt vmcnt(0)" ::: "memory");
      __builtin_amdgcn_s_barrier();
    }
  }

  if constexpr (MODE == 0) {
    float* C = (float*)Cout;
#pragma unroll
    for (int m = 0; m < 4; ++m)
#pragma unroll
      for (int n = 0; n < 8; ++n)
#pragma unroll
        for (int r = 0; r < 4; ++r)
          C[(size_t)(row0 + wr * 64 + m * 16 + 4 * lg + r) * N +
            col0 + wc * 128 + n * 16 + lr] = acc[m][n][r];
  } else {
    // MODE 1: qkv output with fused per-head RMSNorm + RoPE (v: plain).
    unsigned short* C = (unsigned short*)Cout;
    const int hcol0 = col0 + wc * 128;       // head-aligned (128-col) base
    if (col0 >= 3072) {                       // v region: plain bf16
#pragma unroll
      for (int m = 0; m < 4; ++m)
#pragma unroll
        for (int n = 0; n < 8; ++n)
#pragma unroll
          for (int r = 0; r < 4; ++r)
            C[(size_t)(row0 + wr * 64 + m * 16 + 4 * lg + r) * N +
              hcol0 + n * 16 + lr] = f2bf(acc[m][n][r]);
    } else {
      const bool isq = (col0 < 2048);
      const float scq = isq ? SCALE_Q_LOG2E : 1.0f;
      const float* w = isq ? qw : kw;
      float wv[8], fr[4];
#pragma unroll
      for (int n = 0; n < 8; ++n) wv[n] = w[n * 16 + lr];
#pragma unroll
      for (int j = 0; j < 4; ++j)
        fr[j] = exp2f(-(float)(j * 16 + lr) * 0.20762050593045951f);
#pragma unroll
      for (int m = 0; m < 4; ++m)
#pragma unroll
        for (int r = 0; r < 4; ++r) {
          const int row = row0 + wr * 64 + m * 16 + 4 * lg + r;
          // RMS over the head's 128 cols: in-lane n-sum + lr shfl tree
          float ss = 0.f;
#pragma unroll
          for (int n = 0; n < 8; ++n) ss += acc[m][n][r] * acc[m][n][r];
#pragma unroll
          for (int st = 1; st < 16; st <<= 1) ss += __shfl_xor(ss, st, 64);
          float rn = rsqrtf(ss * (1.0f / 128.0f) + 1e-6f);
          float p = (float)pos[row];
          unsigned short* Cr = C + (size_t)row * N + hcol0;
#pragma unroll
          for (int n = 0; n < 4; ++n) {
            float x1 = acc[m][n][r] * rn * wv[n];
            float x2 = acc[m][n + 4][r] * rn * wv[n + 4];
            float ang = p * fr[n];
            float cs = __cosf(ang), sn = __sinf(ang);
            Cr[n * 16 + lr]       = f2bf((x1 * cs - x2 * sn) * scq);
            Cr[(n + 4) * 16 + lr] = f2bf((x2 * cs + x1 * sn) * scq);
          }
        }
    }
  }
}

// ---------------- flash attention, 8-warp swapped-QK^T structure ----------------
// grid (S/256, B*NH); 8 waves x 32 q-rows. 32x32x16 MFMA.
// R24-exact (measured best 369.6us): KVBLK=128 (16 tiles), single-barrier
// tile loop, XCD remap, PV tr-read pipeline over 8 ks-groups, permlane
// repack, log2-domain softmax via raw v_exp_f32, no setprio. LDS 128KB,
// VGPR 128, 1 block/CU. (R25 post-mortem: 16-wave block forced VGPR=64 ->
// wholesale scratch spill, 3.6x regression. 8 waves is the ceiling for
// this register footprint.)
__global__ __launch_bounds__(512, 2) void k_attn(const unsigned short* __restrict__ qkv,
                                                 unsigned short* __restrict__ ctx) {
  const int tid = threadIdx.x;
  const int lane = tid & 63;
  const int wid = tid >> 6;
  const int hi = lane >> 5;
  const int l15 = lane & 15;
  const int q31 = lane & 31;
  // XCD remap: give each XCD 8 consecutive bh (= 4 (b,kvh) K/V sets = 2MB, L2-fits)
  const int lid0 = blockIdx.y * 8 + blockIdx.x;
  const int xcd = lid0 & 7, idx = lid0 >> 3;
  const int bh = xcd * 8 + (idx & 7);
  const int qb = idx >> 3;
  const int b = bh >> 4, h = bh & 15, kvh = h >> 1;

  __shared__ __align__(16) unsigned short Ks[2][128 * 128];
  __shared__ __align__(16) unsigned short Vs[2][128 * 128];

  const size_t baseRow = (size_t)b * S_LEN;
  const int qrow = qb * 256 + wid * 32 + q31;

  const unsigned short* Qg = qkv + (baseRow + qrow) * QKV_N + h * 128;
  short8 qf[8];
#pragma unroll
  for (int c = 0; c < 8; ++c)
    qf[c] = *(const short8*)(Qg + c * 16 + hi * 8);

  const unsigned short* Kg = qkv + baseRow * QKV_N + 2048 + kvh * 128;
  const unsigned short* Vg = Kg + 1024;

  size_t ksrc[4], vsrc[4];
  unsigned sdst[4];
#pragma unroll
  for (int i = 0; i < 4; ++i) {
    int s = tid + i * 512;              // 0..2047: 2048 16B chunks per 32KB tile
    int krow = s >> 4, kc = s & 15;     // 128 rows x 16 chunks
    ksrc[i] = (size_t)krow * QKV_N + (size_t)((kc ^ (krow & 7)) * 8);
    int st = s >> 3, in8 = s & 7;       // 256 subtiles x 8 chunks
    int vkey = (st >> 3) * 4 + (in8 >> 1);   // 0..127
    int vj = ((st & 7) << 1) | (in8 & 1);    // 0..15
    vsrc[i] = (size_t)vkey * QKV_N + (size_t)(vj * 8);
    sdst[i] = (unsigned)s * 16;
  }

#define STAGE(T, BUF)                                                    \
  {                                                                      \
    size_t toff = (size_t)(T) * 128 * QKV_N;                             \
    GLL16(Kg + toff + ksrc[0], (char*)Ks[BUF] + sdst[0]);                \
    GLL16(Kg + toff + ksrc[1], (char*)Ks[BUF] + sdst[1]);                \
    GLL16(Kg + toff + ksrc[2], (char*)Ks[BUF] + sdst[2]);                \
    GLL16(Kg + toff + ksrc[3], (char*)Ks[BUF] + sdst[3]);                \
    GLL16(Vg + toff + vsrc[0], (char*)Vs[BUF] + sdst[0]);                \
    GLL16(Vg + toff + vsrc[1], (char*)Vs[BUF] + sdst[1]);                \
    GLL16(Vg + toff + vsrc[2], (char*)Vs[BUF] + sdst[2]);                \
    GLL16(Vg + toff + vsrc[3], (char*)Vs[BUF] + sdst[3]);                \
  }

  f32x16 acc[4];
#pragma unroll
  for (int d = 0; d < 4; ++d)
#pragma unroll
    for (int r = 0; r < 16; ++r) acc[d][r] = 0.f;
  float m_run = -1e30f, l_run = 0.f;

  const unsigned vbase = (unsigned)(uintptr_t)&Vs[0][0];
  const int sw = (q31 & 7) << 4;

  // issue 8 tr-reads for one ks-group into vr[8]
  auto tr_issue = [&](uint2v* vr, int ksg, unsigned vb) {
#pragma unroll
    for (int db = 0; db < 4; ++db)
#pragma unroll
      for (int rd = 0; rd < 2; ++rd) {
        int st = (ksg * 4 + hi * 2 + rd) * 8 + db * 2 + ((lane >> 4) & 1);
        unsigned a = vb + (unsigned)(st * 128 + l15 * 8);
        asm volatile("ds_read_b64_tr_b16 %0, %1" : "=v"(vr[db * 2 + rd]) : "v"(a));
      }
  };

  STAGE(0, 0);

  for (int t = 0; t < 16; ++t) {
    const int cur = t & 1;
    asm volatile("s_waitcnt vmcnt(0)" ::: "memory");
    __builtin_amdgcn_s_barrier();
    __builtin_amdgcn_sched_barrier(0);
    if (t < 15) STAGE(t + 1, cur ^ 1);

    // ---- QK^T (swapped): p[key][q], lane owns q-row = lane&31 ----
    const char* Kb = (const char*)Ks[cur];
    f32x16 p0, p1, p2, p3;
#pragma unroll
    for (int r = 0; r < 16; ++r) { p0[r] = 0.f; p1[r] = 0.f; p2[r] = 0.f; p3[r] = 0.f; }
#pragma unroll
    for (int c = 0; c < 8; ++c) {
      int cb = c * 32 + hi * 16;
      short8 k0 = *(const short8*)(Kb + (q31      ) * 256 + (cb ^ sw));
      short8 k1 = *(const short8*)(Kb + (q31 + 32 ) * 256 + (cb ^ sw));
      short8 k2 = *(const short8*)(Kb + (q31 + 64 ) * 256 + (cb ^ sw));
      short8 k3 = *(const short8*)(Kb + (q31 + 96 ) * 256 + (cb ^ sw));
      p0 = __builtin_amdgcn_mfma_f32_32x32x16_bf16(k0, qf[c], p0, 0, 0, 0);
      p1 = __builtin_amdgcn_mfma_f32_32x32x16_bf16(k1, qf[c], p1, 0, 0, 0);
      p2 = __builtin_amdgcn_mfma_f32_32x32x16_bf16(k2, qf[c], p2, 0, 0, 0);
      p3 = __builtin_amdgcn_mfma_f32_32x32x16_bf16(k3, qf[c], p3, 0, 0, 0);
    }

    // ---- online softmax (log2 domain, raw v_exp_f32), in-lane ----
    float mt = p0[0];
#pragma unroll
    for (int r = 1; r < 16; ++r) mt = fmaxf(mt, p0[r]);
#pragma unroll
    for (int r = 0; r < 16; ++r) mt = fmaxf(mt, p1[r]);
#pragma unroll
    for (int r = 0; r < 16; ++r) mt = fmaxf(mt, p2[r]);
#pragma unroll
    for (int r = 0; r < 16; ++r) mt = fmaxf(mt, p3[r]);
    mt = fmaxf(mt, __shfl_xor(mt, 32, 64));
    if (!__all(mt - m_run <= 8.0f)) {     // defer-max: P bounded by 2^8
      float mnew = fmaxf(m_run, mt);
      float corr = EXP2F(m_run - mnew);
      l_run *= corr;
#pragma unroll
      for (int d = 0; d < 4; ++d)
#pragma unroll
        for (int r = 0; r < 16; ++r) acc[d][r] *= corr;
      m_run = mnew;
    }
    float s_loc = 0.f;
#pragma unroll
    for (int r = 0; r < 16; ++r) { p0[r] = EXP2F(p0[r] - m_run); s_loc += p0[r]; }
#pragma unroll
    for (int r = 0; r < 16; ++r) { p1[r] = EXP2F(p1[r] - m_run); s_loc += p1[r]; }
#pragma unroll
    for (int r = 0; r < 16; ++r) { p2[r] = EXP2F(p2[r] - m_run); s_loc += p2[r]; }
#pragma unroll
    for (int r = 0; r < 16; ++r) { p3[r] = EXP2F(p3[r] - m_run); s_loc += p3[r]; }
    l_run += s_loc + __shfl_xor(s_loc, 32, 64);

    // ---- PV (swapped): acc[d][q] += V^T x P; tr-reads pipelined 1 group ahead ----
    const unsigned vb = vbase + (unsigned)cur * 32768u;
    const float* pp0 = (const float*)&p0;
    const float* pp1 = (const float*)&p1;
    const float* pp2 = (const float*)&p2;
    const float* pp3 = (const float*)&p3;
    uint2v vrA[8], vrB[8];
    tr_issue(vrA, 0, vb);
#pragma unroll
    for (int ks = 0; ks < 8; ++ks) {
      const int pv = ks >> 1;
      const float* pb = (pv == 0) ? pp0 : (pv == 1) ? pp1 : (pv == 2) ? pp2 : pp3;
      const float* pr = pb + (ks & 1) * 8;
      unsigned t0, t1, u0, u1;
      asm("v_cvt_pk_bf16_f32 %0, %1, %2" : "=v"(t0) : "v"(pr[0]), "v"(pr[1]));
      asm("v_cvt_pk_bf16_f32 %0, %1, %2" : "=v"(t1) : "v"(pr[2]), "v"(pr[3]));
      asm("v_cvt_pk_bf16_f32 %0, %1, %2" : "=v"(u0) : "v"(pr[4]), "v"(pr[5]));
      asm("v_cvt_pk_bf16_f32 %0, %1, %2" : "=v"(u1) : "v"(pr[6]), "v"(pr[7]));
      // cross-half repack in VALU (R3/R4/R9-validated): distinct source values,
      // no CSE-aliasing hazard (t0!=u0, t1!=u1 by construction)
      asm("v_permlane32_swap_b32 %0, %1" : "+v"(t0), "+v"(u0));
      asm("v_permlane32_swap_b32 %0, %1" : "+v"(t1), "+v"(u1));
      union { unsigned u[4]; short8 s; } pa;
      pa.u[0] = t0; pa.u[1] = t1; pa.u[2] = u0; pa.u[3] = u1;

      if (ks + 1 < 8) tr_issue((ks & 1) ? vrA : vrB, ks + 1, vb);

      if (ks < 7) asm volatile("s_waitcnt lgkmcnt(8)" ::: "memory");
      else        asm volatile("s_waitcnt lgkmcnt(0)" ::: "memory");
      __builtin_amdgcn_sched_barrier(0);
#pragma unroll
      for (int db = 0; db < 4; ++db) {
        union { uint2v v[2]; short8 s; } vf;
        if (ks & 1) { vf.v[0] = vrB[db * 2]; vf.v[1] = vrB[db * 2 + 1]; }
        else        { vf.v[0] = vrA[db * 2]; vf.v[1] = vrA[db * 2 + 1]; }
        acc[db] = __builtin_amdgcn_mfma_f32_32x32x16_bf16(vf.s, pa.s, acc[db], 0, 0, 0);
      }
    }
  }

  // ---- epilogue: O^T accum -> ctx[q][d], lane writes its own q-row ----
  float inv = 1.0f / l_run;
  unsigned short* Co = ctx + (baseRow + qrow) * 2048 + h * 128;
#pragma unroll
  for (int db = 0; db < 4; ++db)
#pragma unroll
    for (int g = 0; g < 4; ++g) {
      ushortv4 v;
#pragma unroll
      for (int j = 0; j < 4; ++j) v[j] = f2bf(acc[db][4 * g + j] * inv);
      *(ushortv4*)(Co + db * 32 + g * 8 + hi * 4) = v;
    }
#undef STAGE
}

extern "C" void kernel_launch(void* const* d_in, const int* in_sizes, int n_in,
                              void* d_out, int out_size, void* d_ws, size_t ws_size,
                              hipStream_t stream) {
  const int* positions = (const int*)d_in[0];
  const float* hidden = (const float*)d_in[1];
  const float* w_qkv = (const float*)d_in[2];
  const float* q_norm_w = (const float*)d_in[3];
  const float* k_norm_w = (const float*)d_in[4];
  const float* w_o = (const float*)d_in[5];
  float* out = (float*)d_out;

  char* ws = (char*)d_ws;
  unsigned short* hA    = (unsigned short*)(ws);              // 8192x2048 bf16, reused as ctx
  unsigned short* wqkvT = (unsigned short*)(ws + 33554432);   // 4096x2048 bf16
  unsigned short* woT   = (unsigned short*)(ws + 50331648);   // 2048x2048 bf16
  unsigned short* qkv   = (unsigned short*)(ws + 58720256);   // 8192x4096 bf16
  unsigned short* ctx   = hA;

  // fused prep: cvt + both weight transposes in one launch
  k_prep<<<19456, 256, 0, stream>>>(hidden, hA, w_qkv, wqkvT, w_o, woT);
  // qkv = hidden @ w_qkv with fused RMSNorm+RoPE epilogue (M=8192,N=4096,K=2048)
  k_gemm256<1><<<dim3(16, 32), 512, 0, stream>>>(hA, wqkvT, qkv, 8192, 4096, 2048,
                                                 positions, q_norm_w, k_norm_w);
  k_attn<<<dim3(8, 64), 512, 0, stream>>>(qkv, ctx);
  // out = ctx @ w_o : M=8192, N=2048, K=2048, f32 out
  k_gemm256<0><<<dim3(8, 32), 512, 0, stream>>>(ctx, woT, out, 8192, 2048, 2048,
                                                nullptr, nullptr, nullptr);
}

// Round 27
// 367.410 us; speedup vs baseline: 2.2624x; 1.0079x over previous
//
#include <hip/hip_runtime.h>

#define S_LEN 2048
#define QKV_N 4096
// SCALE_Q * log2(e): logits land in log2 domain, softmax uses v_exp_f32 (exp2)
#define SCALE_Q_LOG2E 0.12751744461f

typedef __attribute__((ext_vector_type(8))) short short8;
typedef __attribute__((ext_vector_type(4))) float f32x4;
typedef __attribute__((ext_vector_type(16))) float f32x16;
typedef __attribute__((ext_vector_type(4))) float floatv4;
typedef __attribute__((ext_vector_type(4))) unsigned short ushortv4;
typedef __attribute__((ext_vector_type(2))) unsigned int uint2v;

__device__ __forceinline__ float bf2f(unsigned short u) {
  union { unsigned u; float f; } x; x.u = ((unsigned)u) << 16; return x.f;
}
__device__ __forceinline__ unsigned short f2bf(float f) {
  union { float f; unsigned u; } x; x.f = f;
  unsigned r = x.u + 0x7fffu + ((x.u >> 16) & 1u);
  return (unsigned short)(r >> 16);
}

typedef const unsigned int __attribute__((address_space(1)))* gas1_t;
typedef unsigned int __attribute__((address_space(3)))* las3_t;
#define GLL16(g, l) __builtin_amdgcn_global_load_lds((gas1_t)(const void*)(g), (las3_t)(void*)(l), 16, 0, 0)

// fast exp2: raw v_exp_f32, no libm fixup path
#define EXP2F(x) __builtin_amdgcn_exp2f(x)

// ---------------- fused prep: cvt (hidden f32->bf16) + 2 transposes ----------------
__global__ __launch_bounds__(256) void k_prep(const float* __restrict__ hidden,
                                              unsigned short* __restrict__ hA,
                                              const float* __restrict__ w_qkv,
                                              unsigned short* __restrict__ wqkvT,
                                              const float* __restrict__ w_o,
                                              unsigned short* __restrict__ woT) {
  __shared__ float t[64][65];
  const int blk = blockIdx.x;
  if (blk < 16384) {
    int i = blk * 256 + threadIdx.x;
    floatv4 v = ((const floatv4*)hidden)[i];
    ushortv4 o;
    o[0] = f2bf(v[0]); o[1] = f2bf(v[1]); o[2] = f2bf(v[2]); o[3] = f2bf(v[3]);
    ((ushortv4*)hA)[i] = o;
    return;
  }
  const float* in;
  unsigned short* out;
  int bx, by, R, C;
  if (blk < 18432) {
    in = w_qkv; out = wqkvT; R = 2048; C = 4096;
    int bi = blk - 16384; bx = bi & 63; by = bi >> 6;
  } else {
    in = w_o; out = woT; R = 2048; C = 2048;
    int bi = blk - 18432; bx = bi & 31; by = bi >> 5;
  }
#pragma unroll
  for (int i = 0; i < 16; ++i) {
    int idx = threadIdx.x + i * 256;
    int r = idx >> 6, c = idx & 63;
    t[r][c] = in[(size_t)(by * 64 + r) * C + bx * 64 + c];
  }
  __syncthreads();
#pragma unroll
  for (int i = 0; i < 16; ++i) {
    int idx = threadIdx.x + i * 256;
    int r = idx >> 6, c = idx & 63;
    out[(size_t)(bx * 64 + r) * R + by * 64 + c] = f2bf(t[c][r]);
  }
}

// ---------------- 256x256x(BK=64) bf16 GEMM, 8 waves, 4-phase pipelined ----------------
// R19/R21-exact (measured best): 4M x 2N waves (wave = one head in MODE 1),
// fused norm+rope epilogue, setprio ON (R18 A/B: +5us/GEMM here), vmcnt(0)
// drain at p==3 (structurally required -- R20 post-mortem).
template <int MODE>
__global__ __launch_bounds__(512, 2) void k_gemm256(const unsigned short* __restrict__ A,
                                                    const unsigned short* __restrict__ BT,
                                                    void* __restrict__ Cout,
                                                    int M, int N, int K,
                                                    const int* __restrict__ pos,
                                                    const float* __restrict__ qw,
                                                    const float* __restrict__ kw) {
  const int tid = threadIdx.x;
  const int lane = tid & 63;
  const int wid = tid >> 6;
  const int wr = wid >> 1;          // 0..3 over M (64 rows each)
  const int wc = wid & 1;           // 0..1 over N (128 cols each)
  const int lr = lane & 15, lg = lane >> 4;

  // T1: bijective XCD-aware block swizzle (nwg % 8 == 0)
  const int gx = gridDim.x;
  const int nwg = gx * gridDim.y;
  const int lid = blockIdx.y * gx + blockIdx.x;
  const int qc = nwg >> 3;
  const int swz = (lid & 7) * qc + (lid >> 3);
  const int row0 = (swz / gx) * 256, col0 = (swz % gx) * 256;

  __shared__ __align__(16) unsigned short As[2][256 * 64];
  __shared__ __align__(16) unsigned short Bs[2][256 * 64];

  f32x4 acc[4][8];
#pragma unroll
  for (int m = 0; m < 4; ++m)
#pragma unroll
    for (int n = 0; n < 8; ++n) acc[m][n] = (f32x4){0.f, 0.f, 0.f, 0.f};

  const int r1 = tid >> 3, c1 = tid & 7;
  const int r2 = (tid + 512) >> 3, c2 = (tid + 512) & 7;
  const size_t so1 = (size_t)r1 * K + (size_t)((c1 ^ (r1 & 7)) * 8);
  const size_t so2 = (size_t)r2 * K + (size_t)((c2 ^ (r2 & 7)) * 8);
  const unsigned ld1 = (unsigned)tid * 16, ld2 = (unsigned)(tid + 512) * 16;

  const unsigned short* Abase = A + (size_t)row0 * K;
  const unsigned short* Bbase = BT + (size_t)col0 * K;

  auto stage = [&](int ph, int kt, int buf) {
    const size_t hb = (size_t)(ph >> 1) * 128 * K + (size_t)kt * 64;
    const unsigned short* src;
    unsigned short* dst;
    if (ph & 1) { src = Bbase + hb; dst = &Bs[buf][(ph >> 1) * 128 * 64]; }
    else        { src = Abase + hb; dst = &As[buf][(ph >> 1) * 128 * 64]; }
    GLL16(src + so1, (char*)dst + ld1);
    GLL16(src + so2, (char*)dst + ld2);
  };

#pragma unroll
  for (int ph = 0; ph < 4; ++ph) stage(ph, 0, 0);
  asm volatile("s_waitcnt vmcnt(0)" ::: "memory");
  __builtin_amdgcn_s_barrier();

  const int NT = K >> 6;
  for (int t = 0; t < NT; ++t) {
    const int cur = t & 1;
    const char* Ab = (const char*)&As[cur][0];
    const char* Bb = (const char*)&Bs[cur][0];
    short8 af[4];
#pragma unroll
    for (int p = 0; p < 4; ++p) {
      const int ks = p >> 1, half = p & 1;
      short8 bf[4];
      if (half == 0) {
#pragma unroll
        for (int m = 0; m < 4; ++m) {
          int rA = wr * 64 + m * 16 + lr;
          af[m] = *(const short8*)(Ab +
                  ((rA * 128 + (ks * 4 + lg) * 16) ^ ((rA & 7) << 4)));
        }
      }
#pragma unroll
      for (int n = 0; n < 4; ++n) {
        int rB = wc * 128 + (half * 4 + n) * 16 + lr;
        bf[n] = *(const short8*)(Bb +
                ((rB * 128 + (ks * 4 + lg) * 16) ^ ((rB & 7) << 4)));
      }
      if (t + 1 < NT) stage(p, t + 1, cur ^ 1);
      __builtin_amdgcn_sched_barrier(0);
      __builtin_amdgcn_s_setprio(1);
#pragma unroll
      for (int m = 0; m < 4; ++m)
#pragma unroll
        for (int n = 0; n < 4; ++n)
          acc[m][half * 4 + n] = __builtin_amdgcn_mfma_f32_16x16x32_bf16(
              af[m], bf[n], acc[m][half * 4 + n], 0, 0, 0);
      __builtin_amdgcn_s_setprio(0);
      if (p == 3) asm volatile("s_waitcnt vmcnt(0)" ::: "memory");
      __builtin_amdgcn_s_barrier();
    }
  }

  if constexpr (MODE == 0) {
    float* C = (float*)Cout;
#pragma unroll
    for (int m = 0; m < 4; ++m)
#pragma unroll
      for (int n = 0; n < 8; ++n)
#pragma unroll
        for (int r = 0; r < 4; ++r)
          C[(size_t)(row0 + wr * 64 + m * 16 + 4 * lg + r) * N +
            col0 + wc * 128 + n * 16 + lr] = acc[m][n][r];
  } else {
    // MODE 1: qkv output with fused per-head RMSNorm + RoPE (v: plain).
    unsigned short* C = (unsigned short*)Cout;
    const int hcol0 = col0 + wc * 128;       // head-aligned (128-col) base
    if (col0 >= 3072) {                       // v region: plain bf16
#pragma unroll
      for (int m = 0; m < 4; ++m)
#pragma unroll
        for (int n = 0; n < 8; ++n)
#pragma unroll
          for (int r = 0; r < 4; ++r)
            C[(size_t)(row0 + wr * 64 + m * 16 + 4 * lg + r) * N +
              hcol0 + n * 16 + lr] = f2bf(acc[m][n][r]);
    } else {
      const bool isq = (col0 < 2048);
      const float scq = isq ? SCALE_Q_LOG2E : 1.0f;
      const float* w = isq ? qw : kw;
      float wv[8], fr[4];
#pragma unroll
      for (int n = 0; n < 8; ++n) wv[n] = w[n * 16 + lr];
#pragma unroll
      for (int j = 0; j < 4; ++j)
        fr[j] = exp2f(-(float)(j * 16 + lr) * 0.20762050593045951f);
#pragma unroll
      for (int m = 0; m < 4; ++m)
#pragma unroll
        for (int r = 0; r < 4; ++r) {
          const int row = row0 + wr * 64 + m * 16 + 4 * lg + r;
          // RMS over the head's 128 cols: in-lane n-sum + lr shfl tree
          float ss = 0.f;
#pragma unroll
          for (int n = 0; n < 8; ++n) ss += acc[m][n][r] * acc[m][n][r];
#pragma unroll
          for (int st = 1; st < 16; st <<= 1) ss += __shfl_xor(ss, st, 64);
          float rn = rsqrtf(ss * (1.0f / 128.0f) + 1e-6f);
          float p = (float)pos[row];
          unsigned short* Cr = C + (size_t)row * N + hcol0;
#pragma unroll
          for (int n = 0; n < 4; ++n) {
            float x1 = acc[m][n][r] * rn * wv[n];
            float x2 = acc[m][n + 4][r] * rn * wv[n + 4];
            float ang = p * fr[n];
            float cs = __cosf(ang), sn = __sinf(ang);
            Cr[n * 16 + lr]       = f2bf((x1 * cs - x2 * sn) * scq);
            Cr[(n + 4) * 16 + lr] = f2bf((x2 * cs + x1 * sn) * scq);
          }
        }
    }
  }
}

// ---------------- flash attention, 8-warp swapped-QK^T structure ----------------
// grid (S/256, B*NH); 8 waves x 32 q-rows. 32x32x16 MFMA. KVBLK=128.
// R27: R24-exact except the cross-half l-sum is DEFERRED to the epilogue.
// Lanes l and l^32 hold the same q-row (q31=lane&31), so mt/m_run/corr are
// pairwise-equal every tile -> per-half partial l sums scale identically
// under rescale; one cross-half add at the end is algebraically exact.
// Saves 1 ds_bpermute + 1 serial dep per tile on the busy LDS pipe.
__global__ __launch_bounds__(512, 2) void k_attn(const unsigned short* __restrict__ qkv,
                                                 unsigned short* __restrict__ ctx) {
  const int tid = threadIdx.x;
  const int lane = tid & 63;
  const int wid = tid >> 6;
  const int hi = lane >> 5;
  const int l15 = lane & 15;
  const int q31 = lane & 31;
  // XCD remap: give each XCD 8 consecutive bh (= 4 (b,kvh) K/V sets = 2MB, L2-fits)
  const int lid0 = blockIdx.y * 8 + blockIdx.x;
  const int xcd = lid0 & 7, idx = lid0 >> 3;
  const int bh = xcd * 8 + (idx & 7);
  const int qb = idx >> 3;
  const int b = bh >> 4, h = bh & 15, kvh = h >> 1;

  __shared__ __align__(16) unsigned short Ks[2][128 * 128];
  __shared__ __align__(16) unsigned short Vs[2][128 * 128];

  const size_t baseRow = (size_t)b * S_LEN;
  const int qrow = qb * 256 + wid * 32 + q31;

  const unsigned short* Qg = qkv + (baseRow + qrow) * QKV_N + h * 128;
  short8 qf[8];
#pragma unroll
  for (int c = 0; c < 8; ++c)
    qf[c] = *(const short8*)(Qg + c * 16 + hi * 8);

  const unsigned short* Kg = qkv + baseRow * QKV_N + 2048 + kvh * 128;
  const unsigned short* Vg = Kg + 1024;

  size_t ksrc[4], vsrc[4];
  unsigned sdst[4];
#pragma unroll
  for (int i = 0; i < 4; ++i) {
    int s = tid + i * 512;              // 0..2047: 2048 16B chunks per 32KB tile
    int krow = s >> 4, kc = s & 15;     // 128 rows x 16 chunks
    ksrc[i] = (size_t)krow * QKV_N + (size_t)((kc ^ (krow & 7)) * 8);
    int st = s >> 3, in8 = s & 7;       // 256 subtiles x 8 chunks
    int vkey = (st >> 3) * 4 + (in8 >> 1);   // 0..127
    int vj = ((st & 7) << 1) | (in8 & 1);    // 0..15
    vsrc[i] = (size_t)vkey * QKV_N + (size_t)(vj * 8);
    sdst[i] = (unsigned)s * 16;
  }

#define STAGE(T, BUF)                                                    \
  {                                                                      \
    size_t toff = (size_t)(T) * 128 * QKV_N;                             \
    GLL16(Kg + toff + ksrc[0], (char*)Ks[BUF] + sdst[0]);                \
    GLL16(Kg + toff + ksrc[1], (char*)Ks[BUF] + sdst[1]);                \
    GLL16(Kg + toff + ksrc[2], (char*)Ks[BUF] + sdst[2]);                \
    GLL16(Kg + toff + ksrc[3], (char*)Ks[BUF] + sdst[3]);                \
    GLL16(Vg + toff + vsrc[0], (char*)Vs[BUF] + sdst[0]);                \
    GLL16(Vg + toff + vsrc[1], (char*)Vs[BUF] + sdst[1]);                \
    GLL16(Vg + toff + vsrc[2], (char*)Vs[BUF] + sdst[2]);                \
    GLL16(Vg + toff + vsrc[3], (char*)Vs[BUF] + sdst[3]);                \
  }

  f32x16 acc[4];
#pragma unroll
  for (int d = 0; d < 4; ++d)
#pragma unroll
    for (int r = 0; r < 16; ++r) acc[d][r] = 0.f;
  float m_run = -1e30f, l_run = 0.f;   // l_run: own-half partial only

  const unsigned vbase = (unsigned)(uintptr_t)&Vs[0][0];
  const int sw = (q31 & 7) << 4;

  // issue 8 tr-reads for one ks-group into vr[8]
  auto tr_issue = [&](uint2v* vr, int ksg, unsigned vb) {
#pragma unroll
    for (int db = 0; db < 4; ++db)
#pragma unroll
      for (int rd = 0; rd < 2; ++rd) {
        int st = (ksg * 4 + hi * 2 + rd) * 8 + db * 2 + ((lane >> 4) & 1);
        unsigned a = vb + (unsigned)(st * 128 + l15 * 8);
        asm volatile("ds_read_b64_tr_b16 %0, %1" : "=v"(vr[db * 2 + rd]) : "v"(a));
      }
  };

  STAGE(0, 0);

  for (int t = 0; t < 16; ++t) {
    const int cur = t & 1;
    asm volatile("s_waitcnt vmcnt(0)" ::: "memory");
    __builtin_amdgcn_s_barrier();
    __builtin_amdgcn_sched_barrier(0);
    if (t < 15) STAGE(t + 1, cur ^ 1);

    // ---- QK^T (swapped): p[key][q], lane owns q-row = lane&31 ----
    const char* Kb = (const char*)Ks[cur];
    f32x16 p0, p1, p2, p3;
#pragma unroll
    for (int r = 0; r < 16; ++r) { p0[r] = 0.f; p1[r] = 0.f; p2[r] = 0.f; p3[r] = 0.f; }
#pragma unroll
    for (int c = 0; c < 8; ++c) {
      int cb = c * 32 + hi * 16;
      short8 k0 = *(const short8*)(Kb + (q31      ) * 256 + (cb ^ sw));
      short8 k1 = *(const short8*)(Kb + (q31 + 32 ) * 256 + (cb ^ sw));
      short8 k2 = *(const short8*)(Kb + (q31 + 64 ) * 256 + (cb ^ sw));
      short8 k3 = *(const short8*)(Kb + (q31 + 96 ) * 256 + (cb ^ sw));
      p0 = __builtin_amdgcn_mfma_f32_32x32x16_bf16(k0, qf[c], p0, 0, 0, 0);
      p1 = __builtin_amdgcn_mfma_f32_32x32x16_bf16(k1, qf[c], p1, 0, 0, 0);
      p2 = __builtin_amdgcn_mfma_f32_32x32x16_bf16(k2, qf[c], p2, 0, 0, 0);
      p3 = __builtin_amdgcn_mfma_f32_32x32x16_bf16(k3, qf[c], p3, 0, 0, 0);
    }

    // ---- online softmax (log2 domain, raw v_exp_f32), in-lane ----
    float mt = p0[0];
#pragma unroll
    for (int r = 1; r < 16; ++r) mt = fmaxf(mt, p0[r]);
#pragma unroll
    for (int r = 0; r < 16; ++r) mt = fmaxf(mt, p1[r]);
#pragma unroll
    for (int r = 0; r < 16; ++r) mt = fmaxf(mt, p2[r]);
#pragma unroll
    for (int r = 0; r < 16; ++r) mt = fmaxf(mt, p3[r]);
    mt = fmaxf(mt, __shfl_xor(mt, 32, 64));
    if (!__all(mt - m_run <= 8.0f)) {     // defer-max: P bounded by 2^8
      float mnew = fmaxf(m_run, mt);
      float corr = EXP2F(m_run - mnew);
      l_run *= corr;
#pragma unroll
      for (int d = 0; d < 4; ++d)
#pragma unroll
        for (int r = 0; r < 16; ++r) acc[d][r] *= corr;
      m_run = mnew;
    }
    float s_loc = 0.f;
#pragma unroll
    for (int r = 0; r < 16; ++r) { p0[r] = EXP2F(p0[r] - m_run); s_loc += p0[r]; }
#pragma unroll
    for (int r = 0; r < 16; ++r) { p1[r] = EXP2F(p1[r] - m_run); s_loc += p1[r]; }
#pragma unroll
    for (int r = 0; r < 16; ++r) { p2[r] = EXP2F(p2[r] - m_run); s_loc += p2[r]; }
#pragma unroll
    for (int r = 0; r < 16; ++r) { p3[r] = EXP2F(p3[r] - m_run); s_loc += p3[r]; }
    l_run += s_loc;   // own-half partial; cross-half add deferred to epilogue

    // ---- PV (swapped): acc[d][q] += V^T x P; tr-reads pipelined 1 group ahead ----
    const unsigned vb = vbase + (unsigned)cur * 32768u;
    const float* pp0 = (const float*)&p0;
    const float* pp1 = (const float*)&p1;
    const float* pp2 = (const float*)&p2;
    const float* pp3 = (const float*)&p3;
    uint2v vrA[8], vrB[8];
    tr_issue(vrA, 0, vb);
#pragma unroll
    for (int ks = 0; ks < 8; ++ks) {
      const int pv = ks >> 1;
      const float* pb = (pv == 0) ? pp0 : (pv == 1) ? pp1 : (pv == 2) ? pp2 : pp3;
      const float* pr = pb + (ks & 1) * 8;
      unsigned t0, t1, u0, u1;
      asm("v_cvt_pk_bf16_f32 %0, %1, %2" : "=v"(t0) : "v"(pr[0]), "v"(pr[1]));
      asm("v_cvt_pk_bf16_f32 %0, %1, %2" : "=v"(t1) : "v"(pr[2]), "v"(pr[3]));
      asm("v_cvt_pk_bf16_f32 %0, %1, %2" : "=v"(u0) : "v"(pr[4]), "v"(pr[5]));
      asm("v_cvt_pk_bf16_f32 %0, %1, %2" : "=v"(u1) : "v"(pr[6]), "v"(pr[7]));
      // cross-half repack in VALU (R3/R4/R9-validated): distinct source values,
      // no CSE-aliasing hazard (t0!=u0, t1!=u1 by construction)
      asm("v_permlane32_swap_b32 %0, %1" : "+v"(t0), "+v"(u0));
      asm("v_permlane32_swap_b32 %0, %1" : "+v"(t1), "+v"(u1));
      union { unsigned u[4]; short8 s; } pa;
      pa.u[0] = t0; pa.u[1] = t1; pa.u[2] = u0; pa.u[3] = u1;

      if (ks + 1 < 8) tr_issue((ks & 1) ? vrA : vrB, ks + 1, vb);

      if (ks < 7) asm volatile("s_waitcnt lgkmcnt(8)" ::: "memory");
      else        asm volatile("s_waitcnt lgkmcnt(0)" ::: "memory");
      __builtin_amdgcn_sched_barrier(0);
#pragma unroll
      for (int db = 0; db < 4; ++db) {
        union { uint2v v[2]; short8 s; } vf;
        if (ks & 1) { vf.v[0] = vrB[db * 2]; vf.v[1] = vrB[db * 2 + 1]; }
        else        { vf.v[0] = vrA[db * 2]; vf.v[1] = vrA[db * 2 + 1]; }
        acc[db] = __builtin_amdgcn_mfma_f32_32x32x16_bf16(vf.s, pa.s, acc[db], 0, 0, 0);
      }
    }
  }

  // ---- epilogue: finish cross-half l, then O^T -> ctx[q][d] ----
  float inv = 1.0f / (l_run + __shfl_xor(l_run, 32, 64));
  unsigned short* Co = ctx + (baseRow + qrow) * 2048 + h * 128;
#pragma unroll
  for (int db = 0; db < 4; ++db)
#pragma unroll
    for (int g = 0; g < 4; ++g) {
      ushortv4 v;
#pragma unroll
      for (int j = 0; j < 4; ++j) v[j] = f2bf(acc[db][4 * g + j] * inv);
      *(ushortv4*)(Co + db * 32 + g * 8 + hi * 4) = v;
    }
#undef STAGE
}

extern "C" void kernel_launch(void* const* d_in, const int* in_sizes, int n_in,
                              void* d_out, int out_size, void* d_ws, size_t ws_size,
                              hipStream_t stream) {
  const int* positions = (const int*)d_in[0];
  const float* hidden = (const float*)d_in[1];
  const float* w_qkv = (const float*)d_in[2];
  const float* q_norm_w = (const float*)d_in[3];
  const float* k_norm_w = (const float*)d_in[4];
  const float* w_o = (const float*)d_in[5];
  float* out = (float*)d_out;

  char* ws = (char*)d_ws;
  unsigned short* hA    = (unsigned short*)(ws);              // 8192x2048 bf16, reused as ctx
  unsigned short* wqkvT = (unsigned short*)(ws + 33554432);   // 4096x2048 bf16
  unsigned short* woT   = (unsigned short*)(ws + 50331648);   // 2048x2048 bf16
  unsigned short* qkv   = (unsigned short*)(ws + 58720256);   // 8192x4096 bf16
  unsigned short* ctx   = hA;

  // fused prep: cvt + both weight transposes in one launch
  k_prep<<<19456, 256, 0, stream>>>(hidden, hA, w_qkv, wqkvT, w_o, woT);
  // qkv = hidden @ w_qkv with fused RMSNorm+RoPE epilogue (M=8192,N=4096,K=2048)
  k_gemm256<1><<<dim3(16, 32), 512, 0, stream>>>(hA, wqkvT, qkv, 8192, 4096, 2048,
                                                 positions, q_norm_w, k_norm_w);
  k_attn<<<dim3(8, 64), 512, 0, stream>>>(qkv, ctx);
  // out = ctx @ w_o : M=8192, N=2048, K=2048, f32 out
  k_gemm256<0><<<dim3(8, 32), 512, 0, stream>>>(ctx, woT, out, 8192, 2048, 2048,
                                                nullptr, nullptr, nullptr);
}